// Round 2
// baseline (148.058 us; speedup 1.0000x reference)
//
#include <hip/hip_runtime.h>

#define T_LEN 262144
#define R_LEN 4000
#define NCH 64
#define V_OFF 4032
#define NCHUNK 252      // K=16 chunks: v = 32 + 16*p + (8*h + e)
#define WIN 36864       // staged window elems per block (36768 used, padded)

typedef __attribute__((ext_vector_type(8))) short bf16x8;
typedef __attribute__((ext_vector_type(16))) float f32x16;

static __device__ __forceinline__ unsigned short f2bf(float f) {
  unsigned u = __builtin_bit_cast(unsigned, f);
  unsigned r = 0x7FFFu + ((u >> 16) & 1u);
  return (unsigned short)((u + r) >> 16);
}

// Btf[((ch*252 + p)*64 + lane)*8 + e] = k_ch[4000 + (lane&31) - 16p - 8*(lane>>5) - e]
// (zero outside [0,4000)) -- B[v][j] = k[V_OFF + j - v], v = 32 + 16p + 8h + e, j = lane&31
__global__ __launch_bounds__(256) void build_btf(const float* __restrict__ src,
                                                 unsigned short* __restrict__ btf) {
  int t = blockIdx.x * 256 + threadIdx.x;
  if (t >= NCH * NCHUNK * 64) return;
  int lane = t & 63;
  int p = (t >> 6) % NCHUNK;
  int ch = t / (64 * NCHUNK);
  int j = lane & 31;
  int h = lane >> 5;
  int kbase = 4000 + j - 16 * p - 8 * h;
  const float* k = src + (size_t)ch * R_LEN;
  unsigned short vals[8];
#pragma unroll
  for (int e = 0; e < 8; ++e) {
    int r = kbase - e;
    float f = (r >= 0 && r < R_LEN) ? k[r] : 0.0f;
    vals[e] = f2bf(f);
  }
  unsigned int* dst = (unsigned int*)(btf + (size_t)t * 8);
  dst[0] = (unsigned int)vals[0] | ((unsigned int)vals[1] << 16);
  dst[1] = (unsigned int)vals[2] | ((unsigned int)vals[3] << 16);
  dst[2] = (unsigned int)vals[4] | ((unsigned int)vals[5] << 16);
  dst[3] = (unsigned int)vals[6] | ((unsigned int)vals[7] << 16);
}

// Block: channel ch = bid&63, piece = bid>>6 -> 32768 outputs at T0 = piece*32768.
// Wave w: 8 tiles of 1024 outputs at TB = T0 + 8192*w + 1024*m.
// D_m[i][j] = out[TB + 1024m + 32*i + j] = sum_v A[i][v] B[v][j]
// A[i][v] = x[TB + 1024m + 32i + v - 4032], staged bf16 window xs.
// Window element u = 8192w + 1024m + 32i + 16p + 8h (+e); byte b = 2u, XOR-swizzled.
__global__ __launch_bounds__(256, 2) void conv_main(const float* __restrict__ x,
                                                    const unsigned short* __restrict__ btf,
                                                    float* __restrict__ out) {
  __shared__ unsigned short xs[WIN];
  const int bid = blockIdx.x;
  const int ch = bid & 63;          // all 8 pieces of a channel share bid%8 -> same XCD
  const int T0 = (bid >> 6) << 15;
  const float* xch = x + (size_t)ch * T_LEN;

  // Stage: slot s holds bf16(x[T0 - 4000 + 8s .. +8)), written at swizzled byte 16s
  for (int s = threadIdx.x; s < WIN / 8; s += 256) {
    int gi = T0 - 4000 + 8 * s;
    float v0, v1, v2, v3, v4, v5, v6, v7;
    if (gi >= 0 && gi + 8 <= T_LEN) {
      float4 a = *(const float4*)(xch + gi);
      float4 b = *(const float4*)(xch + gi + 4);
      v0 = a.x; v1 = a.y; v2 = a.z; v3 = a.w;
      v4 = b.x; v5 = b.y; v6 = b.z; v7 = b.w;
    } else {
      v0 = (gi + 0 >= 0 && gi + 0 < T_LEN) ? xch[gi + 0] : 0.f;
      v1 = (gi + 1 >= 0 && gi + 1 < T_LEN) ? xch[gi + 1] : 0.f;
      v2 = (gi + 2 >= 0 && gi + 2 < T_LEN) ? xch[gi + 2] : 0.f;
      v3 = (gi + 3 >= 0 && gi + 3 < T_LEN) ? xch[gi + 3] : 0.f;
      v4 = (gi + 4 >= 0 && gi + 4 < T_LEN) ? xch[gi + 4] : 0.f;
      v5 = (gi + 5 >= 0 && gi + 5 < T_LEN) ? xch[gi + 5] : 0.f;
      v6 = (gi + 6 >= 0 && gi + 6 < T_LEN) ? xch[gi + 6] : 0.f;
      v7 = (gi + 7 >= 0 && gi + 7 < T_LEN) ? xch[gi + 7] : 0.f;
    }
    uint4 pk;
    pk.x = (unsigned int)f2bf(v0) | ((unsigned int)f2bf(v1) << 16);
    pk.y = (unsigned int)f2bf(v2) | ((unsigned int)f2bf(v3) << 16);
    pk.z = (unsigned int)f2bf(v4) | ((unsigned int)f2bf(v5) << 16);
    pk.w = (unsigned int)f2bf(v6) | ((unsigned int)f2bf(v7) << 16);
    int b = 16 * s;
    b ^= ((b >> 7) & 1) << 5;
    *(uint4*)((char*)xs + b) = pk;
  }
  __syncthreads();

  const int lane = threadIdx.x & 63;
  const int w = threadIdx.x >> 6;
  const int i = lane & 31;
  const int h = lane >> 5;

  f32x16 acc[8] = {};

  const bf16x8* bp = (const bf16x8*)btf + (size_t)ch * NCHUNK * 64 + lane;
  const int abase = 16384 * w + 64 * i + 16 * h;   // byte offset, pre-swizzle

#pragma unroll 2
  for (int p = 0; p < NCHUNK; ++p) {
    bf16x8 bfrag = bp[p * 64];
#pragma unroll
    for (int m = 0; m < 8; ++m) {
      int b = abase + 32 * p + 2048 * m;
      b ^= ((b >> 7) & 1) << 5;
      bf16x8 afrag = *(const bf16x8*)((const char*)xs + b);
      acc[m] = __builtin_amdgcn_mfma_f32_32x32x16_bf16(afrag, bfrag, acc[m], 0, 0, 0);
    }
  }

  // C/D layout (verified): col = lane&31, row = (reg&3) + 8*(reg>>2) + 4*(lane>>5)
  float* och = out + (size_t)ch * T_LEN + T0 + 8192 * w;
#pragma unroll
  for (int m = 0; m < 8; ++m) {
#pragma unroll
    for (int r = 0; r < 16; ++r) {
      int row = (r & 3) + 8 * (r >> 2) + 4 * h;
      och[1024 * m + 32 * row + i] = acc[m][r];
    }
  }
}

extern "C" void kernel_launch(void* const* d_in, const int* in_sizes, int n_in,
                              void* d_out, int out_size, void* d_ws, size_t ws_size,
                              hipStream_t stream) {
  const float* onsets  = (const float*)d_in[0];
  const float* sources = (const float*)d_in[1];
  unsigned short* btf  = (unsigned short*)d_ws;   // 64*252*64*8*2 = 16,515,072 B
  float* out = (float*)d_out;

  int nthr = NCH * NCHUNK * 64;
  build_btf<<<(nthr + 255) / 256, 256, 0, stream>>>(sources, btf);
  conv_main<<<512, 256, 0, stream>>>(onsets, btf, out);
}

// Round 3
// 115.050 us; speedup vs baseline: 1.2869x; 1.2869x over previous
//
#include <hip/hip_runtime.h>

#define T_LEN 262144
#define R_LEN 4000
#define NCH 64
#define NCHUNK 253      // table chunks t in [0,253); nonzero only [0,252); 252 = zero pad
#define WIN_SLOTS 4608  // 16B staging slots (36864 bf16 elems)
#define LDS_BYTES 73984 // 2312 blocks x 32B (2304 data blocks, permuted beta'=(b>>3)+(b&7)*289)

typedef __attribute__((ext_vector_type(8))) short bf16x8;
typedef __attribute__((ext_vector_type(16))) float f32x16;

static __device__ __forceinline__ unsigned short f2bf(float f) {
  unsigned u = __builtin_bit_cast(unsigned, f);
  unsigned r = 0x7FFFu + ((u >> 16) & 1u);
  return (unsigned short)((u + r) >> 16);
}

// T[t][j,h,e] = k[4000 + j - 16t - 8h - e] (zero outside [0,4000))
// stored: btf[((ch*253 + t)*64 + lane)*8 + e], j = lane&31, h = lane>>5
__global__ __launch_bounds__(256) void build_btf(const float* __restrict__ src,
                                                 unsigned short* __restrict__ btf) {
  int t0 = blockIdx.x * 256 + threadIdx.x;
  if (t0 >= NCH * NCHUNK * 64) return;
  int lane = t0 & 63;
  int t = (t0 >> 6) % NCHUNK;
  int ch = t0 / (64 * NCHUNK);
  int j = lane & 31;
  int h = lane >> 5;
  int kbase = 4000 + j - 16 * t - 8 * h;
  const float* k = src + (size_t)ch * R_LEN;
  unsigned short vals[8];
#pragma unroll
  for (int e = 0; e < 8; ++e) {
    int r = kbase - e;
    float f = (r >= 0 && r < R_LEN) ? k[r] : 0.0f;
    vals[e] = f2bf(f);
  }
  unsigned int* dst = (unsigned int*)(btf + (size_t)t0 * 8);
  dst[0] = (unsigned int)vals[0] | ((unsigned int)vals[1] << 16);
  dst[1] = (unsigned int)vals[2] | ((unsigned int)vals[3] << 16);
  dst[2] = (unsigned int)vals[4] | ((unsigned int)vals[5] << 16);
  dst[3] = (unsigned int)vals[6] | ((unsigned int)vals[7] << 16);
}

// Block: ch = bid&63, piece = bid>>6 (8 pieces of 32768 outputs). Wave w: 8192 outputs.
// Tile (m,c): D[i][j] = out[TB + 4096m + 128i + j + 32c] = sum_q A_m[q] . T[q-2c]
// A_m lane(i,h) at step q: window elem u = 8192w + 4096m + 128i + 16q + 8h  (byte 2u)
// LDS permute: 32B-block beta -> (beta>>3) + (beta&7)*289  => reads contiguous 1024B.
__global__ __launch_bounds__(256, 2) void conv_main(const float* __restrict__ x,
                                                    const unsigned short* __restrict__ btf,
                                                    float* __restrict__ out) {
  __shared__ alignas(16) unsigned char xs[LDS_BYTES];
  const int bid = blockIdx.x;
  const int ch = bid & 63;
  const int T0 = (bid >> 6) << 15;
  const float* xch = x + (size_t)ch * T_LEN;

  // Stage slot s: bf16(x[T0-4000+8s .. +8)) at permuted block (s>>1), half (s&1)
  for (int s = threadIdx.x; s < WIN_SLOTS; s += 256) {
    int gi = T0 - 4000 + 8 * s;
    float v0, v1, v2, v3, v4, v5, v6, v7;
    if (gi >= 0 && gi + 8 <= T_LEN) {
      float4 a = *(const float4*)(xch + gi);
      float4 b = *(const float4*)(xch + gi + 4);
      v0 = a.x; v1 = a.y; v2 = a.z; v3 = a.w;
      v4 = b.x; v5 = b.y; v6 = b.z; v7 = b.w;
    } else {
      v0 = (gi + 0 >= 0 && gi + 0 < T_LEN) ? xch[gi + 0] : 0.f;
      v1 = (gi + 1 >= 0 && gi + 1 < T_LEN) ? xch[gi + 1] : 0.f;
      v2 = (gi + 2 >= 0 && gi + 2 < T_LEN) ? xch[gi + 2] : 0.f;
      v3 = (gi + 3 >= 0 && gi + 3 < T_LEN) ? xch[gi + 3] : 0.f;
      v4 = (gi + 4 >= 0 && gi + 4 < T_LEN) ? xch[gi + 4] : 0.f;
      v5 = (gi + 5 >= 0 && gi + 5 < T_LEN) ? xch[gi + 5] : 0.f;
      v6 = (gi + 6 >= 0 && gi + 6 < T_LEN) ? xch[gi + 6] : 0.f;
      v7 = (gi + 7 >= 0 && gi + 7 < T_LEN) ? xch[gi + 7] : 0.f;
    }
    uint4 pk;
    pk.x = (unsigned int)f2bf(v0) | ((unsigned int)f2bf(v1) << 16);
    pk.y = (unsigned int)f2bf(v2) | ((unsigned int)f2bf(v3) << 16);
    pk.z = (unsigned int)f2bf(v4) | ((unsigned int)f2bf(v5) << 16);
    pk.w = (unsigned int)f2bf(v6) | ((unsigned int)f2bf(v7) << 16);
    int beta = s >> 1;
    int bp = (((beta >> 3) + (beta & 7) * 289) << 5) + 16 * (s & 1);
    *(uint4*)(xs + bp) = pk;
  }
  __syncthreads();

  const int lane = threadIdx.x & 63;
  const int w = threadIdx.x >> 6;
  const int i = lane & 31;
  const int h = lane >> 5;
  const int lanepart = 32 * i + 16 * h;
  const char* bbase = (const char*)btf + ((size_t)ch * NCHUNK) * 1024 + (size_t)lane * 16;

  auto aread = [&](int m, int q) -> bf16x8 {
    int b0 = 512 * w + 256 * m + q;
    int addr = (((b0 >> 3) + (b0 & 7) * 289) << 5) + lanepart;
    return *(const bf16x8*)(xs + addr);
  };
  auto bload = [&](int t) -> bf16x8 {
    int tc = t > 252 ? 252 : t;   // chunks [252,253) are zeros; clamp keeps in-table
    return *(const bf16x8*)(bbase + (size_t)tc * 1024);
  };

  f32x16 acc[2][4] = {};
  bf16x8 zero8 = {};
  bf16x8 E0 = bload(0), E1 = zero8, E2 = zero8, E3 = zero8;
  bf16x8 O0 = bload(1), O1 = zero8, O2 = zero8, O3 = zero8;
  bf16x8 a0 = aread(0, 0), a1 = aread(1, 0);

#define DO_STEP(B0, B1, B2, B3, QQ)                                                      \
  {                                                                                      \
    bf16x8 nb = bload((QQ) + 2);                                                         \
    bf16x8 a0n = aread(0, (QQ) + 1);                                                     \
    bf16x8 a1n = aread(1, (QQ) + 1);                                                     \
    acc[0][0] = __builtin_amdgcn_mfma_f32_32x32x16_bf16(a0, B0, acc[0][0], 0, 0, 0);     \
    acc[0][1] = __builtin_amdgcn_mfma_f32_32x32x16_bf16(a0, B1, acc[0][1], 0, 0, 0);     \
    acc[0][2] = __builtin_amdgcn_mfma_f32_32x32x16_bf16(a0, B2, acc[0][2], 0, 0, 0);     \
    acc[0][3] = __builtin_amdgcn_mfma_f32_32x32x16_bf16(a0, B3, acc[0][3], 0, 0, 0);     \
    acc[1][0] = __builtin_amdgcn_mfma_f32_32x32x16_bf16(a1, B0, acc[1][0], 0, 0, 0);     \
    acc[1][1] = __builtin_amdgcn_mfma_f32_32x32x16_bf16(a1, B1, acc[1][1], 0, 0, 0);     \
    acc[1][2] = __builtin_amdgcn_mfma_f32_32x32x16_bf16(a1, B2, acc[1][2], 0, 0, 0);     \
    acc[1][3] = __builtin_amdgcn_mfma_f32_32x32x16_bf16(a1, B3, acc[1][3], 0, 0, 0);     \
    B3 = B2; B2 = B1; B1 = B0; B0 = nb;                                                  \
    a0 = a0n; a1 = a1n;                                                                  \
  }

#pragma unroll 4
  for (int q = 0; q < 258; q += 2) {
    DO_STEP(E0, E1, E2, E3, q);
    DO_STEP(O0, O1, O2, O3, q + 1);
  }
#undef DO_STEP

  // C/D layout: col j = lane&31, row = (r&3) + 8*(r>>2) + 4*h
  float* och = out + (size_t)ch * T_LEN + T0 + 8192 * w;
#pragma unroll
  for (int m = 0; m < 2; ++m) {
#pragma unroll
    for (int c = 0; c < 4; ++c) {
#pragma unroll
      for (int r = 0; r < 16; ++r) {
        int row = (r & 3) + 8 * (r >> 2) + 4 * h;
        och[4096 * m + 32 * c + 128 * row + i] = acc[m][c][r];
      }
    }
  }
}

extern "C" void kernel_launch(void* const* d_in, const int* in_sizes, int n_in,
                              void* d_out, int out_size, void* d_ws, size_t ws_size,
                              hipStream_t stream) {
  const float* onsets  = (const float*)d_in[0];
  const float* sources = (const float*)d_in[1];
  unsigned short* btf  = (unsigned short*)d_ws;   // 64*253*64*8*2 = 16,580,608 B
  float* out = (float*)d_out;

  int nthr = NCH * NCHUNK * 64;
  build_btf<<<(nthr + 255) / 256, 256, 0, stream>>>(sources, btf);
  conv_main<<<512, 256, 0, stream>>>(onsets, btf, out);
}